// Round 8
// baseline (371.826 us; speedup 1.0000x reference)
//
#include <hip/hip_runtime.h>
#include <hip/hip_fp16.h>
#include <math.h>

#define N_NODES 50000
#define N_EDGES 600000
#define D_IN    128
#define D_HID   256
#define D_OUT   128
#define NB_SCAN ((N_NODES + 255) / 256)   // 196

typedef unsigned short u16;
typedef unsigned long long u64;
typedef __attribute__((ext_vector_type(8))) _Float16 f16x8;
typedef __attribute__((ext_vector_type(4))) float f32x4;
// native ext-vector types for nontemporal builtins (HIP_vector_type rejected)
typedef __attribute__((ext_vector_type(2))) float f32x2v;
typedef __attribute__((ext_vector_type(4))) float f32x4v;
typedef __attribute__((ext_vector_type(2))) unsigned int u32x2v;
typedef __attribute__((ext_vector_type(2))) u16 u16x2v;
typedef __attribute__((ext_vector_type(4))) u16 u16x4v;

// packed degcnt layout: [rank:20 bits (63..44)][sum_fixed:44 bits (43..0)], scale 2^20
#define DC_SHIFT 44
#define DC_SCALE 1048576.0f
#define DC_MASK  ((1ULL << DC_SHIFT) - 1ULL)

#define WPREP_TOTAL 131072
#define CAST_TOTAL  (N_NODES * 32)   // x [N,128] f32 as float4 groups

__device__ __forceinline__ u16 f2h(float x) {
    __half h = __float2half_rn(x);
    return *reinterpret_cast<u16*>(&h);
}
__device__ __forceinline__ float h2f(u16 h) {
    __half hh = *reinterpret_cast<__half*>(&h);
    return __half2float(hh);
}
__device__ __forceinline__ float2 h2f2(unsigned int raw) {
    __half2 h = *reinterpret_cast<__half2*>(&raw);
    return __half22float2(h);
}
__device__ __forceinline__ int bcast_i(int v, int l) {
    return __builtin_amdgcn_readlane(v, l);
}
__device__ __forceinline__ float bcast_f(float v, int l) {
    return __int_as_float(__builtin_amdgcn_readlane(__float_as_int(v), l));
}

// ---------------------------------------------------------------------------
// k_setup0: three INDEPENDENT phases fused in one dispatch (no sync needed):
//   A) hist: one packed u64 atomic per edge (rank | fixed-point weighted deg)
//   B) cast x f32 -> xh fp16 [N,128]   (rides in hist's latency shadow)
//   C) wprep: W -> fp16 hi/lo planes   (ditto)
// ---------------------------------------------------------------------------
__global__ __launch_bounds__(256) void k_setup0(
        const int* __restrict__ dst, const float* __restrict__ wts,
        float* __restrict__ ew, int* __restrict__ rank,
        u64* __restrict__ degcnt,
        const float* __restrict__ x, u16* __restrict__ xh,
        const float* __restrict__ W1, const float* __restrict__ W2,
        const float* __restrict__ W3,
        u16* __restrict__ B1, u16* __restrict__ B2, u16* __restrict__ B3) {
    int gid = blockIdx.x * blockDim.x + threadIdx.x;
    int stride = gridDim.x * blockDim.x;

    // A: histogram
    for (int e = gid; e < N_EDGES; e += stride) {
        float v = wts[e];
        float sp = fmaxf(v, 0.f) + log1pf(expf(-fabsf(v)));
        ew[e] = sp;
        int d = dst[e];
        u64 pack = (1ULL << DC_SHIFT) + (u64)__float2uint_rn(sp * DC_SCALE);
        u64 old = atomicAdd(&degcnt[d], pack);
        rank[e] = (int)(old >> DC_SHIFT);
    }
    // B: x -> fp16
    for (int g = gid; g < CAST_TOTAL; g += stride) {
        float4 v = reinterpret_cast<const float4*>(x)[g];
        u16x4v h = {f2h(v.x), f2h(v.y), f2h(v.z), f2h(v.w)};
        reinterpret_cast<u16x4v*>(xh)[g] = h;
    }
    // C: weight prep
    for (int g = gid; g < WPREP_TOTAL; g += stride) {
        const float* W; u16* B; int K, N, base;
        if (g < 32768)      { W = W1; B = B1; K = 128; N = 256; base = 0; }
        else if (g < 98304) { W = W2; B = B2; K = 256; N = 256; base = 32768; }
        else                { W = W3; B = B3; K = 256; N = 128; base = 98304; }
        int p = g - base;
        int n = p % N, k = p / N;
        float v = W[(size_t)k * N + n];
        u16 hi = f2h(v);
        u16 lo = f2h(v - h2f(hi));
        B[(size_t)n * (2 * K) + k] = hi;
        B[(size_t)n * (2 * K) + K + k] = lo;
    }
}

__global__ void k_scan1(const u64* __restrict__ degcnt, int* __restrict__ rowptr,
                        int* __restrict__ bsum) {
    __shared__ int s[256];
    int b = blockIdx.x, t = threadIdx.x;
    int i = b * 256 + t;
    // count lives in the high u32 word (little-endian): hi >> (44-32)
    int v = (i < N_NODES)
          ? (int)(reinterpret_cast<const unsigned int*>(degcnt)[2 * i + 1] >> (DC_SHIFT - 32))
          : 0;
    s[t] = v;
    __syncthreads();
    for (int off = 1; off < 256; off <<= 1) {
        int u = (t >= off) ? s[t - off] : 0;
        __syncthreads();
        s[t] += u;
        __syncthreads();
    }
    if (i < N_NODES) rowptr[i] = s[t] - v;
    if (t == 255) bsum[b] = s[255];
}

// fused scan2+scan3+dinv: every block re-scans the 196-entry bsum in LDS.
__global__ void k_scan23(const int* __restrict__ bsum, int* __restrict__ rowptr,
                         const u64* __restrict__ degcnt, float* __restrict__ dinv) {
    __shared__ int s[256];
    __shared__ int orig[256];
    int b = blockIdx.x, t = threadIdx.x;
    int v = (t < NB_SCAN) ? bsum[t] : 0;
    s[t] = v;
    orig[t] = v;
    __syncthreads();
    for (int off = 1; off < 256; off <<= 1) {
        int u = (t >= off) ? s[t - off] : 0;
        __syncthreads();
        s[t] += u;
        __syncthreads();
    }
    int boffb = s[b] - orig[b];   // exclusive prefix for this block
    int i = b * 256 + t;
    if (i < N_NODES) {
        rowptr[i] += boffb;
        float deg = (float)(degcnt[i] & DC_MASK) * (1.0f / DC_SCALE);
        dinv[i] = rsqrtf(1.0f + deg);
    }
    if (b == 0 && t == 0) rowptr[N_NODES] = s[NB_SCAN - 1];
}

__global__ void k_fill2(const int* __restrict__ src, const int* __restrict__ dst,
                        const float* __restrict__ ew, const int* __restrict__ rank,
                        const int* __restrict__ rowptr, const float* __restrict__ dinv,
                        int2* __restrict__ ecsr) {
    int e = blockIdx.x * blockDim.x + threadIdx.x;
    if (e >= N_EDGES) return;
    int s = src[e], d = dst[e];
    int pos = rowptr[d] + rank[e];
    float wfin = dinv[s] * ew[e] * dinv[d];
    ecsr[pos] = make_int2(s, __float_as_int(wfin));
}

// ---------------------------------------------------------------------------
// Aggregation. INF: 0 = f32 rows, 1 = fp16 rows. OUTM: 0 = f32 (+bias),
// 1 = fp16 [N, D]. One wave per node. Cooperative edge-header load +
// readlane broadcast; 8-deep gather pipeline. Nontemporal output stores +
// header loads.
// ---------------------------------------------------------------------------

template <int D, int INF, int OUTM, bool BIAS>
__global__ __launch_bounds__(256) void k_agg(const void* __restrict__ inv,
                                             const int* __restrict__ rowptr,
                                             const int2* __restrict__ ecsr,
                                             const float* __restrict__ dinv,
                                             const float* __restrict__ bias,
                                             void* __restrict__ outv) {
    int node = blockIdx.x * 4 + (threadIdx.x >> 6);
    int lane = threadIdx.x & 63;
    if (node >= N_NODES) return;
    float dn = dinv[node];
    float dd = dn * dn;
    int beg = rowptr[node], end = rowptr[node + 1];
    int deg = end - beg;
    // cooperative header fetch: lane i holds edge (beg+i); avg deg ~12.
    int esrc = 0;
    float ewv = 0.f;
    if (lane < deg) {
        u32x2v t = __builtin_nontemporal_load(
            reinterpret_cast<const u32x2v*>(ecsr) + beg + lane);
        esrc = (int)t.x;
        ewv = __uint_as_float(t.y);
    }
    int dcap = (deg > 64) ? 64 : deg;

    if (D == 256) {
        const float* inf = (const float*)inv;
        const u16* inh = (const u16*)inv;
        float ax, ay, az, aw;
        if (INF == 0) {
            float4 sv = *(reinterpret_cast<const float4*>(inf + (size_t)node * D) + lane);
            ax = dd * sv.x; ay = dd * sv.y; az = dd * sv.z; aw = dd * sv.w;
        } else {
            uint2 raw = *reinterpret_cast<const uint2*>(inh + (size_t)node * D + lane * 4);
            float2 f01 = h2f2(raw.x), f23 = h2f2(raw.y);
            ax = dd * f01.x; ay = dd * f01.y; az = dd * f23.x; aw = dd * f23.y;
        }
        int j = 0;
        for (; j + 8 <= dcap; j += 8) {
            int si[8]; float wv[8];
            #pragma unroll
            for (int k = 0; k < 8; ++k) {
                si[k] = bcast_i(esrc, j + k);
                wv[k] = bcast_f(ewv, j + k);
            }
            if (INF == 0) {
                float4 r[8];
                #pragma unroll
                for (int k = 0; k < 8; ++k)
                    r[k] = *(reinterpret_cast<const float4*>(inf + (size_t)si[k] * D) + lane);
                #pragma unroll
                for (int k = 0; k < 8; ++k) {
                    ax += wv[k] * r[k].x; ay += wv[k] * r[k].y;
                    az += wv[k] * r[k].z; aw += wv[k] * r[k].w;
                }
            } else {
                uint2 q[8];
                #pragma unroll
                for (int k = 0; k < 8; ++k)
                    q[k] = *reinterpret_cast<const uint2*>(inh + (size_t)si[k] * D + lane * 4);
                #pragma unroll
                for (int k = 0; k < 8; ++k) {
                    float2 a = h2f2(q[k].x), b = h2f2(q[k].y);
                    ax += wv[k] * a.x; ay += wv[k] * a.y;
                    az += wv[k] * b.x; aw += wv[k] * b.y;
                }
            }
        }
        for (; j < dcap; ++j) {
            int s0 = bcast_i(esrc, j);
            float w0 = bcast_f(ewv, j);
            if (INF == 0) {
                float4 r0 = *(reinterpret_cast<const float4*>(inf + (size_t)s0 * D) + lane);
                ax += w0 * r0.x; ay += w0 * r0.y; az += w0 * r0.z; aw += w0 * r0.w;
            } else {
                uint2 q0 = *reinterpret_cast<const uint2*>(inh + (size_t)s0 * D + lane * 4);
                float2 a0 = h2f2(q0.x), b0 = h2f2(q0.y);
                ax += w0 * a0.x; ay += w0 * a0.y; az += w0 * b0.x; aw += w0 * b0.y;
            }
        }
        for (int p = beg + 64; p < end; ++p) {  // deg>64 tail (statistically never)
            int2 e0 = ecsr[p];
            float w0 = __int_as_float(e0.y);
            if (INF == 0) {
                float4 r0 = *(reinterpret_cast<const float4*>(inf + (size_t)e0.x * D) + lane);
                ax += w0 * r0.x; ay += w0 * r0.y; az += w0 * r0.z; aw += w0 * r0.w;
            } else {
                uint2 q0 = *reinterpret_cast<const uint2*>(inh + (size_t)e0.x * D + lane * 4);
                float2 a0 = h2f2(q0.x), b0 = h2f2(q0.y);
                ax += w0 * a0.x; ay += w0 * a0.y; az += w0 * b0.x; aw += w0 * b0.y;
            }
        }
        if (OUTM == 0) {
            float* out = (float*)outv;
            if (BIAS) {
                float4 b = *(reinterpret_cast<const float4*>(bias) + lane);
                ax += b.x; ay += b.y; az += b.z; aw += b.w;
            }
            f32x4v res = {ax, ay, az, aw};
            __builtin_nontemporal_store(res,
                reinterpret_cast<f32x4v*>(out + (size_t)node * D) + lane);
        } else {
            u16* out = (u16*)outv;  // fp16 [N, 256]
            u16x4v hv = {f2h(ax), f2h(ay), f2h(az), f2h(aw)};
            __builtin_nontemporal_store(hv,
                reinterpret_cast<u16x4v*>(out + (size_t)node * D + lane * 4));
        }
    } else {  // D == 128
        const float* inf = (const float*)inv;
        const u16* inh = (const u16*)inv;
        float ax, ay;
        if (INF == 0) {
            float2 sv = *(reinterpret_cast<const float2*>(inf + (size_t)node * D) + lane);
            ax = dd * sv.x; ay = dd * sv.y;
        } else {
            unsigned int raw = *reinterpret_cast<const unsigned int*>(inh + (size_t)node * D + lane * 2);
            float2 f = h2f2(raw);
            ax = dd * f.x; ay = dd * f.y;
        }
        int j = 0;
        for (; j + 8 <= dcap; j += 8) {
            int si[8]; float wv[8];
            #pragma unroll
            for (int k = 0; k < 8; ++k) {
                si[k] = bcast_i(esrc, j + k);
                wv[k] = bcast_f(ewv, j + k);
            }
            if (INF == 0) {
                float2 r[8];
                #pragma unroll
                for (int k = 0; k < 8; ++k)
                    r[k] = *(reinterpret_cast<const float2*>(inf + (size_t)si[k] * D) + lane);
                #pragma unroll
                for (int k = 0; k < 8; ++k) {
                    ax += wv[k] * r[k].x; ay += wv[k] * r[k].y;
                }
            } else {
                unsigned int q[8];
                #pragma unroll
                for (int k = 0; k < 8; ++k)
                    q[k] = *reinterpret_cast<const unsigned int*>(inh + (size_t)si[k] * D + lane * 2);
                #pragma unroll
                for (int k = 0; k < 8; ++k) {
                    float2 f = h2f2(q[k]);
                    ax += wv[k] * f.x; ay += wv[k] * f.y;
                }
            }
        }
        for (; j < dcap; ++j) {
            int s0 = bcast_i(esrc, j);
            float w0 = bcast_f(ewv, j);
            if (INF == 0) {
                float2 r0 = *(reinterpret_cast<const float2*>(inf + (size_t)s0 * D) + lane);
                ax += w0 * r0.x; ay += w0 * r0.y;
            } else {
                unsigned int q0 = *reinterpret_cast<const unsigned int*>(inh + (size_t)s0 * D + lane * 2);
                float2 f0 = h2f2(q0);
                ax += w0 * f0.x; ay += w0 * f0.y;
            }
        }
        for (int p = beg + 64; p < end; ++p) {  // deg>64 tail
            int2 e0 = ecsr[p];
            float w0 = __int_as_float(e0.y);
            if (INF == 0) {
                float2 r0 = *(reinterpret_cast<const float2*>(inf + (size_t)e0.x * D) + lane);
                ax += w0 * r0.x; ay += w0 * r0.y;
            } else {
                unsigned int q0 = *reinterpret_cast<const unsigned int*>(inh + (size_t)e0.x * D + lane * 2);
                float2 f0 = h2f2(q0);
                ax += w0 * f0.x; ay += w0 * f0.y;
            }
        }
        if (OUTM == 0) {
            float* out = (float*)outv;
            if (BIAS) {
                float2 b = *(reinterpret_cast<const float2*>(bias) + lane);
                ax += b.x; ay += b.y;
            }
            f32x2v res = {ax, ay};
            __builtin_nontemporal_store(res,
                reinterpret_cast<f32x2v*>(out + (size_t)node * D) + lane);
        } else {
            u16* out = (u16*)outv;  // fp16 [N, 128]
            u16x2v hv = {f2h(ax), f2h(ay)};
            __builtin_nontemporal_store(hv,
                reinterpret_cast<u16x2v*>(out + (size_t)node * D + lane * 2));
        }
    }
}

// ---------------------------------------------------------------------------
// fp16 MFMA GEMM with fp16-hilo weights.
// R8: software-pipelined staging — K-step k+1's A/B tiles are prefetched
// into VGPRs while step k's MFMAs run, hiding global-load latency that the
// short (4-8 iter) K-loop cannot amortize otherwise.
// ---------------------------------------------------------------------------

template <int OUT, bool BIAS, bool RELU>
__global__ __launch_bounds__(256) void k_gemm_h(const u16* __restrict__ Ap,
                                                const u16* __restrict__ Bp,
                                                const float* __restrict__ bias,
                                                void* __restrict__ Cv,
                                                int M, int K, int NN) {
    const int KP2 = 2 * K;
    __shared__ u16 As[8 * 544];
    __shared__ u16 Bs[2 * 8 * 544];
    int tid = threadIdx.x;
    int bm = blockIdx.y * 128;
    int bn = blockIdx.x * 128;
    int l = tid & 63;
    int w = tid >> 6;
    int wr = w >> 1, wc = w & 1;

    // staging coordinates (loop-invariant)
    int ga[2], oa[2], la[2];
    #pragma unroll
    for (int q = 0; q < 2; q++) {
        int idx = tid + q * 256;
        int r = idx >> 2, o = idx & 3;
        ga[q] = bm + r;
        oa[q] = o;
        la[q] = (r >> 4) * 544 + o * 136 + (r & 15) * 8;
    }
    size_t gb[4]; int lb[4];
    #pragma unroll
    for (int q = 0; q < 4; q++) {
        int idx = tid + q * 256;
        int r = idx >> 3, oct = idx & 7;
        int hf = oct >> 2, o = oct & 3;
        gb[q] = (size_t)(bn + r) * KP2 + hf * K + o * 8;
        lb[q] = hf * 4352 + (r >> 4) * 544 + o * 136 + (r & 15) * 8;
    }

    f32x4 zero = {0.f, 0.f, 0.f, 0.f};
    f32x4 acc[4][4];
    #pragma unroll
    for (int i = 0; i < 4; i++)
        #pragma unroll
        for (int j = 0; j < 4; j++) acc[i][j] = zero;

    // prefetch k0 = 0
    uint4 va[2], vb[4];
    #pragma unroll
    for (int q = 0; q < 2; q++) {
        va[q] = make_uint4(0u, 0u, 0u, 0u);
        if (ga[q] < M)
            va[q] = *reinterpret_cast<const uint4*>(Ap + (size_t)ga[q] * K + oa[q] * 8);
    }
    #pragma unroll
    for (int q = 0; q < 4; q++)
        vb[q] = *reinterpret_cast<const uint4*>(Bp + gb[q]);

    for (int k0 = 0; k0 < K; k0 += 32) {
        // commit staged registers to LDS
        #pragma unroll
        for (int q = 0; q < 2; q++)
            *reinterpret_cast<uint4*>(&As[la[q]]) = va[q];
        #pragma unroll
        for (int q = 0; q < 4; q++)
            *reinterpret_cast<uint4*>(&Bs[lb[q]]) = vb[q];
        __syncthreads();

        // issue next K-step's loads; latency hides under the MFMAs below
        if (k0 + 32 < K) {
            int kn = k0 + 32;
            #pragma unroll
            for (int q = 0; q < 2; q++) {
                va[q] = make_uint4(0u, 0u, 0u, 0u);
                if (ga[q] < M)
                    va[q] = *reinterpret_cast<const uint4*>(
                        Ap + (size_t)ga[q] * K + kn + oa[q] * 8);
            }
            #pragma unroll
            for (int q = 0; q < 4; q++)
                vb[q] = *reinterpret_cast<const uint4*>(Bp + gb[q] + kn);
        }

        int fro = (l >> 4) * 136 + (l & 15) * 8;
        f16x8 a[4], bh[4], bl[4];
        #pragma unroll
        for (int i = 0; i < 4; i++)
            a[i] = *reinterpret_cast<const f16x8*>(&As[(wr * 4 + i) * 544 + fro]);
        #pragma unroll
        for (int j = 0; j < 4; j++) {
            bh[j] = *reinterpret_cast<const f16x8*>(&Bs[(wc * 4 + j) * 544 + fro]);
            bl[j] = *reinterpret_cast<const f16x8*>(&Bs[4352 + (wc * 4 + j) * 544 + fro]);
        }
        #pragma unroll
        for (int i = 0; i < 4; i++)
            #pragma unroll
            for (int j = 0; j < 4; j++) {
                acc[i][j] = __builtin_amdgcn_mfma_f32_16x16x32_f16(a[i], bh[j], acc[i][j], 0, 0, 0);
                acc[i][j] = __builtin_amdgcn_mfma_f32_16x16x32_f16(a[i], bl[j], acc[i][j], 0, 0, 0);
            }
        __syncthreads();
    }

    int cl = l & 15;
    int rq = (l >> 4) * 4;
    float bv[4];
    #pragma unroll
    for (int j = 0; j < 4; j++) {
        int gc = bn + wc * 64 + j * 16 + cl;
        bv[j] = BIAS ? bias[gc] : 0.f;
    }
    #pragma unroll
    for (int i = 0; i < 4; i++) {
        #pragma unroll
        for (int r = 0; r < 4; r++) {
            int grow = bm + wr * 64 + i * 16 + rq + r;
            if (grow >= M) continue;
            #pragma unroll
            for (int j = 0; j < 4; j++) {
                int gc = bn + wc * 64 + j * 16 + cl;
                float v = acc[i][j][r];
                if (BIAS) v += bv[j];
                if (RELU) v = fmaxf(v, 0.f);
                if (OUT == 0) {
                    ((float*)Cv)[(size_t)grow * NN + gc] = v;
                } else {
                    ((u16*)Cv)[(size_t)grow * NN + gc] = f2h(v);
                }
            }
        }
    }
}

// ---------------------------------------------------------------------------
// launch
// ---------------------------------------------------------------------------

extern "C" void kernel_launch(void* const* d_in, const int* in_sizes, int n_in,
                              void* d_out, int out_size, void* d_ws, size_t ws_size,
                              hipStream_t stream) {
    const float* x   = (const float*)d_in[0];
    const int*   ei  = (const int*)d_in[1];
    const float* wts = (const float*)d_in[2];
    const float* W1  = (const float*)d_in[3];
    const float* b1  = (const float*)d_in[4];
    const float* W2  = (const float*)d_in[5];
    const float* b2  = (const float*)d_in[6];
    const float* W3  = (const float*)d_in[7];
    const float* b3  = (const float*)d_in[8];
    float* out = (float*)d_out;
    const int* src = ei;
    const int* dst = ei + N_EDGES;

    // Layout identical to the verified R1/R5/R7 kernels.
    float* bufA   = (float*)d_ws;                         // fp16 [N,256] max
    float* bufB   = bufA + (size_t)N_NODES * D_HID;       // fp16 [N,256] max (51.2 MB)
    float* ew     = bufB + (size_t)N_NODES * D_HID;       // [E]
    float* dinv   = ew + N_EDGES;                         // [N]
    int*   cnt    = (int*)(dinv + N_NODES);               // [N] (unused now)
    int*   rank   = cnt + N_NODES;                        // [E]
    int*   rowptr = rank + N_EDGES;                       // [N+1]
    int2*  ecsr   = (int2*)(rowptr + (N_NODES + 2));      // [E] packed {src, w}
    u16*   Wb1    = (u16*)(ecsr + N_EDGES);               // [256*256]
    u16*   Wb2    = Wb1 + 256 * 256;                      // [256*512]
    u16*   Wb3    = Wb2 + 256 * 512;                      // [128*512]
    int*   bsum   = (int*)(Wb3 + 128 * 512);              // [NB_SCAN]
    // degcnt (u64[N], 400 KB) in bufB's LOWER half; xh (fp16 [N,128], 12.8 MB)
    // in bufB's UPPER half (offset 25.6 MB). Both dead before gemm1 writes
    // bufB's first 25.6 MB.
    u64*   degcnt = (u64*)bufB;
    u16*   xh     = (u16*)(bufB + (size_t)N_NODES * D_HID / 2);

    (void)hipMemsetAsync(degcnt, 0, sizeof(u64) * N_NODES, stream);

    int ethreads = 256;
    int eblocks = (N_EDGES + ethreads - 1) / ethreads;
    k_setup0<<<eblocks, ethreads, 0, stream>>>(dst, wts, ew, rank, degcnt,
                                               x, xh, W1, W2, W3, Wb1, Wb2, Wb3);
    k_scan1<<<NB_SCAN, 256, 0, stream>>>(degcnt, rowptr, bsum);
    k_scan23<<<NB_SCAN, 256, 0, stream>>>(bsum, rowptr, degcnt, dinv);
    k_fill2<<<eblocks, ethreads, 0, stream>>>(src, dst, ew, rank, rowptr, dinv, ecsr);

    int aggBlocks = (N_NODES + 3) / 4;
    int gy = (N_NODES + 127) / 128;  // 391

    // agg1: xh (fp16) -> bufA fp16 [N,128]
    k_agg<128, 1, 1, false><<<aggBlocks, 256, 0, stream>>>(xh, rowptr, ecsr, dinv, nullptr, bufA);
    // gemm1: h1 = relu(bufA @ W1 + b1) -> bufB fp16 [N,256]
    {
        dim3 g(2, gy);
        k_gemm_h<1, true, true><<<g, 256, 0, stream>>>((const u16*)bufA, Wb1, b1, bufB,
                                                       N_NODES, D_IN, D_HID);
    }
    // agg2: bufB fp16 -> bufA fp16 [N,256]
    k_agg<256, 1, 1, false><<<aggBlocks, 256, 0, stream>>>(bufB, rowptr, ecsr, dinv, nullptr, bufA);
    // gemm2: h2 = relu(bufA @ W2 + b2) -> bufB fp16 [N,256]
    {
        dim3 g(2, gy);
        k_gemm_h<1, true, true><<<g, 256, 0, stream>>>((const u16*)bufA, Wb2, b2, bufB,
                                                       N_NODES, D_HID, D_HID);
    }
    // gemm3: y3 = bufB @ W3 -> bufA fp16 [N,128]
    {
        dim3 g(1, gy);
        k_gemm_h<1, false, false><<<g, 256, 0, stream>>>((const u16*)bufB, Wb3, nullptr, bufA,
                                                         N_NODES, D_HID, D_OUT);
    }
    // agg3: bufA fp16 -> out f32 + b3
    k_agg<128, 1, 0, true><<<aggBlocks, 256, 0, stream>>>(bufA, rowptr, ecsr, dinv, b3, out);
}

// Round 9
// 322.039 us; speedup vs baseline: 1.1546x; 1.1546x over previous
//
#include <hip/hip_runtime.h>
#include <hip/hip_fp16.h>
#include <math.h>

#define N_NODES 50000
#define N_EDGES 600000
#define D_IN    128
#define D_HID   256
#define D_OUT   128
#define NB_SCAN ((N_NODES + 255) / 256)   // 196

typedef unsigned short u16;
typedef unsigned long long u64;
typedef __attribute__((ext_vector_type(8))) _Float16 f16x8;
typedef __attribute__((ext_vector_type(4))) float f32x4;
// native ext-vector types for nontemporal builtins (HIP_vector_type rejected)
typedef __attribute__((ext_vector_type(2))) float f32x2v;
typedef __attribute__((ext_vector_type(4))) float f32x4v;
typedef __attribute__((ext_vector_type(2))) unsigned int u32x2v;
typedef __attribute__((ext_vector_type(2))) u16 u16x2v;
typedef __attribute__((ext_vector_type(4))) u16 u16x4v;

// packed degcnt layout: [rank:20 bits (63..44)][sum_fixed:44 bits (43..0)], scale 2^20
#define DC_SHIFT 44
#define DC_SCALE 1048576.0f
#define DC_MASK  ((1ULL << DC_SHIFT) - 1ULL)

#define WPREP_TOTAL 131072
#define CAST_TOTAL  (N_NODES * 32)   // x [N,128] f32 as float4 groups

__device__ __forceinline__ u16 f2h(float x) {
    __half h = __float2half_rn(x);
    return *reinterpret_cast<u16*>(&h);
}
__device__ __forceinline__ float h2f(u16 h) {
    __half hh = *reinterpret_cast<__half*>(&h);
    return __half2float(hh);
}
__device__ __forceinline__ float2 h2f2(unsigned int raw) {
    __half2 h = *reinterpret_cast<__half2*>(&raw);
    return __half22float2(h);
}
__device__ __forceinline__ int bcast_i(int v, int l) {
    return __builtin_amdgcn_readlane(v, l);
}
__device__ __forceinline__ float bcast_f(float v, int l) {
    return __int_as_float(__builtin_amdgcn_readlane(__float_as_int(v), l));
}

// ---------------------------------------------------------------------------
// k_setup0: three INDEPENDENT phases fused in one dispatch (no sync needed):
//   A) hist: one packed u64 atomic per edge (rank | fixed-point weighted deg)
//   B) cast x f32 -> xh fp16 [N,128]   (rides in hist's latency shadow)
//   C) wprep: W -> fp16 hi/lo planes   (ditto)
// ---------------------------------------------------------------------------
__global__ __launch_bounds__(256) void k_setup0(
        const int* __restrict__ dst, const float* __restrict__ wts,
        float* __restrict__ ew, int* __restrict__ rank,
        u64* __restrict__ degcnt,
        const float* __restrict__ x, u16* __restrict__ xh,
        const float* __restrict__ W1, const float* __restrict__ W2,
        const float* __restrict__ W3,
        u16* __restrict__ B1, u16* __restrict__ B2, u16* __restrict__ B3) {
    int gid = blockIdx.x * blockDim.x + threadIdx.x;
    int stride = gridDim.x * blockDim.x;

    // A: histogram
    for (int e = gid; e < N_EDGES; e += stride) {
        float v = wts[e];
        float sp = fmaxf(v, 0.f) + log1pf(expf(-fabsf(v)));
        ew[e] = sp;
        int d = dst[e];
        u64 pack = (1ULL << DC_SHIFT) + (u64)__float2uint_rn(sp * DC_SCALE);
        u64 old = atomicAdd(&degcnt[d], pack);
        rank[e] = (int)(old >> DC_SHIFT);
    }
    // B: x -> fp16
    for (int g = gid; g < CAST_TOTAL; g += stride) {
        float4 v = reinterpret_cast<const float4*>(x)[g];
        u16x4v h = {f2h(v.x), f2h(v.y), f2h(v.z), f2h(v.w)};
        reinterpret_cast<u16x4v*>(xh)[g] = h;
    }
    // C: weight prep
    for (int g = gid; g < WPREP_TOTAL; g += stride) {
        const float* W; u16* B; int K, N, base;
        if (g < 32768)      { W = W1; B = B1; K = 128; N = 256; base = 0; }
        else if (g < 98304) { W = W2; B = B2; K = 256; N = 256; base = 32768; }
        else                { W = W3; B = B3; K = 256; N = 128; base = 98304; }
        int p = g - base;
        int n = p % N, k = p / N;
        float v = W[(size_t)k * N + n];
        u16 hi = f2h(v);
        u16 lo = f2h(v - h2f(hi));
        B[(size_t)n * (2 * K) + k] = hi;
        B[(size_t)n * (2 * K) + K + k] = lo;
    }
}

__global__ void k_scan1(const u64* __restrict__ degcnt, int* __restrict__ rowptr,
                        int* __restrict__ bsum) {
    __shared__ int s[256];
    int b = blockIdx.x, t = threadIdx.x;
    int i = b * 256 + t;
    // count lives in the high u32 word (little-endian): hi >> (44-32)
    int v = (i < N_NODES)
          ? (int)(reinterpret_cast<const unsigned int*>(degcnt)[2 * i + 1] >> (DC_SHIFT - 32))
          : 0;
    s[t] = v;
    __syncthreads();
    for (int off = 1; off < 256; off <<= 1) {
        int u = (t >= off) ? s[t - off] : 0;
        __syncthreads();
        s[t] += u;
        __syncthreads();
    }
    if (i < N_NODES) rowptr[i] = s[t] - v;
    if (t == 255) bsum[b] = s[255];
}

// fused scan2+scan3+dinv: every block re-scans the 196-entry bsum in LDS.
__global__ void k_scan23(const int* __restrict__ bsum, int* __restrict__ rowptr,
                         const u64* __restrict__ degcnt, float* __restrict__ dinv) {
    __shared__ int s[256];
    __shared__ int orig[256];
    int b = blockIdx.x, t = threadIdx.x;
    int v = (t < NB_SCAN) ? bsum[t] : 0;
    s[t] = v;
    orig[t] = v;
    __syncthreads();
    for (int off = 1; off < 256; off <<= 1) {
        int u = (t >= off) ? s[t - off] : 0;
        __syncthreads();
        s[t] += u;
        __syncthreads();
    }
    int boffb = s[b] - orig[b];   // exclusive prefix for this block
    int i = b * 256 + t;
    if (i < N_NODES) {
        rowptr[i] += boffb;
        float deg = (float)(degcnt[i] & DC_MASK) * (1.0f / DC_SCALE);
        dinv[i] = rsqrtf(1.0f + deg);
    }
    if (b == 0 && t == 0) rowptr[N_NODES] = s[NB_SCAN - 1];
}

__global__ void k_fill2(const int* __restrict__ src, const int* __restrict__ dst,
                        const float* __restrict__ ew, const int* __restrict__ rank,
                        const int* __restrict__ rowptr, const float* __restrict__ dinv,
                        int2* __restrict__ ecsr) {
    int e = blockIdx.x * blockDim.x + threadIdx.x;
    if (e >= N_EDGES) return;
    int s = src[e], d = dst[e];
    int pos = rowptr[d] + rank[e];
    float wfin = dinv[s] * ew[e] * dinv[d];
    ecsr[pos] = make_int2(s, __float_as_int(wfin));
}

// ---------------------------------------------------------------------------
// Aggregation. INF: 0 = f32 rows, 1 = fp16 rows. OUTM: 0 = f32 (+bias),
// 1 = fp16 [N, D]. One wave per node. Cooperative edge-header load +
// readlane broadcast; 8-deep gather pipeline. Nontemporal output stores +
// header loads.
// ---------------------------------------------------------------------------

template <int D, int INF, int OUTM, bool BIAS>
__global__ __launch_bounds__(256) void k_agg(const void* __restrict__ inv,
                                             const int* __restrict__ rowptr,
                                             const int2* __restrict__ ecsr,
                                             const float* __restrict__ dinv,
                                             const float* __restrict__ bias,
                                             void* __restrict__ outv) {
    int node = blockIdx.x * 4 + (threadIdx.x >> 6);
    int lane = threadIdx.x & 63;
    if (node >= N_NODES) return;
    float dn = dinv[node];
    float dd = dn * dn;
    int beg = rowptr[node], end = rowptr[node + 1];
    int deg = end - beg;
    // cooperative header fetch: lane i holds edge (beg+i); avg deg ~12.
    int esrc = 0;
    float ewv = 0.f;
    if (lane < deg) {
        u32x2v t = __builtin_nontemporal_load(
            reinterpret_cast<const u32x2v*>(ecsr) + beg + lane);
        esrc = (int)t.x;
        ewv = __uint_as_float(t.y);
    }
    int dcap = (deg > 64) ? 64 : deg;

    if (D == 256) {
        const float* inf = (const float*)inv;
        const u16* inh = (const u16*)inv;
        float ax, ay, az, aw;
        if (INF == 0) {
            float4 sv = *(reinterpret_cast<const float4*>(inf + (size_t)node * D) + lane);
            ax = dd * sv.x; ay = dd * sv.y; az = dd * sv.z; aw = dd * sv.w;
        } else {
            uint2 raw = *reinterpret_cast<const uint2*>(inh + (size_t)node * D + lane * 4);
            float2 f01 = h2f2(raw.x), f23 = h2f2(raw.y);
            ax = dd * f01.x; ay = dd * f01.y; az = dd * f23.x; aw = dd * f23.y;
        }
        int j = 0;
        for (; j + 8 <= dcap; j += 8) {
            int si[8]; float wv[8];
            #pragma unroll
            for (int k = 0; k < 8; ++k) {
                si[k] = bcast_i(esrc, j + k);
                wv[k] = bcast_f(ewv, j + k);
            }
            if (INF == 0) {
                float4 r[8];
                #pragma unroll
                for (int k = 0; k < 8; ++k)
                    r[k] = *(reinterpret_cast<const float4*>(inf + (size_t)si[k] * D) + lane);
                #pragma unroll
                for (int k = 0; k < 8; ++k) {
                    ax += wv[k] * r[k].x; ay += wv[k] * r[k].y;
                    az += wv[k] * r[k].z; aw += wv[k] * r[k].w;
                }
            } else {
                uint2 q[8];
                #pragma unroll
                for (int k = 0; k < 8; ++k)
                    q[k] = *reinterpret_cast<const uint2*>(inh + (size_t)si[k] * D + lane * 4);
                #pragma unroll
                for (int k = 0; k < 8; ++k) {
                    float2 a = h2f2(q[k].x), b = h2f2(q[k].y);
                    ax += wv[k] * a.x; ay += wv[k] * a.y;
                    az += wv[k] * b.x; aw += wv[k] * b.y;
                }
            }
        }
        for (; j < dcap; ++j) {
            int s0 = bcast_i(esrc, j);
            float w0 = bcast_f(ewv, j);
            if (INF == 0) {
                float4 r0 = *(reinterpret_cast<const float4*>(inf + (size_t)s0 * D) + lane);
                ax += w0 * r0.x; ay += w0 * r0.y; az += w0 * r0.z; aw += w0 * r0.w;
            } else {
                uint2 q0 = *reinterpret_cast<const uint2*>(inh + (size_t)s0 * D + lane * 4);
                float2 a0 = h2f2(q0.x), b0 = h2f2(q0.y);
                ax += w0 * a0.x; ay += w0 * a0.y; az += w0 * b0.x; aw += w0 * b0.y;
            }
        }
        for (int p = beg + 64; p < end; ++p) {  // deg>64 tail (statistically never)
            int2 e0 = ecsr[p];
            float w0 = __int_as_float(e0.y);
            if (INF == 0) {
                float4 r0 = *(reinterpret_cast<const float4*>(inf + (size_t)e0.x * D) + lane);
                ax += w0 * r0.x; ay += w0 * r0.y; az += w0 * r0.z; aw += w0 * r0.w;
            } else {
                uint2 q0 = *reinterpret_cast<const uint2*>(inh + (size_t)e0.x * D + lane * 4);
                float2 a0 = h2f2(q0.x), b0 = h2f2(q0.y);
                ax += w0 * a0.x; ay += w0 * a0.y; az += w0 * b0.x; aw += w0 * b0.y;
            }
        }
        if (OUTM == 0) {
            float* out = (float*)outv;
            if (BIAS) {
                float4 b = *(reinterpret_cast<const float4*>(bias) + lane);
                ax += b.x; ay += b.y; az += b.z; aw += b.w;
            }
            f32x4v res = {ax, ay, az, aw};
            __builtin_nontemporal_store(res,
                reinterpret_cast<f32x4v*>(out + (size_t)node * D) + lane);
        } else {
            u16* out = (u16*)outv;  // fp16 [N, 256]
            u16x4v hv = {f2h(ax), f2h(ay), f2h(az), f2h(aw)};
            __builtin_nontemporal_store(hv,
                reinterpret_cast<u16x4v*>(out + (size_t)node * D + lane * 4));
        }
    } else {  // D == 128
        const float* inf = (const float*)inv;
        const u16* inh = (const u16*)inv;
        float ax, ay;
        if (INF == 0) {
            float2 sv = *(reinterpret_cast<const float2*>(inf + (size_t)node * D) + lane);
            ax = dd * sv.x; ay = dd * sv.y;
        } else {
            unsigned int raw = *reinterpret_cast<const unsigned int*>(inh + (size_t)node * D + lane * 2);
            float2 f = h2f2(raw);
            ax = dd * f.x; ay = dd * f.y;
        }
        int j = 0;
        for (; j + 8 <= dcap; j += 8) {
            int si[8]; float wv[8];
            #pragma unroll
            for (int k = 0; k < 8; ++k) {
                si[k] = bcast_i(esrc, j + k);
                wv[k] = bcast_f(ewv, j + k);
            }
            if (INF == 0) {
                float2 r[8];
                #pragma unroll
                for (int k = 0; k < 8; ++k)
                    r[k] = *(reinterpret_cast<const float2*>(inf + (size_t)si[k] * D) + lane);
                #pragma unroll
                for (int k = 0; k < 8; ++k) {
                    ax += wv[k] * r[k].x; ay += wv[k] * r[k].y;
                }
            } else {
                unsigned int q[8];
                #pragma unroll
                for (int k = 0; k < 8; ++k)
                    q[k] = *reinterpret_cast<const unsigned int*>(inh + (size_t)si[k] * D + lane * 2);
                #pragma unroll
                for (int k = 0; k < 8; ++k) {
                    float2 f = h2f2(q[k]);
                    ax += wv[k] * f.x; ay += wv[k] * f.y;
                }
            }
        }
        for (; j < dcap; ++j) {
            int s0 = bcast_i(esrc, j);
            float w0 = bcast_f(ewv, j);
            if (INF == 0) {
                float2 r0 = *(reinterpret_cast<const float2*>(inf + (size_t)s0 * D) + lane);
                ax += w0 * r0.x; ay += w0 * r0.y;
            } else {
                unsigned int q0 = *reinterpret_cast<const unsigned int*>(inh + (size_t)s0 * D + lane * 2);
                float2 f0 = h2f2(q0);
                ax += w0 * f0.x; ay += w0 * f0.y;
            }
        }
        for (int p = beg + 64; p < end; ++p) {  // deg>64 tail
            int2 e0 = ecsr[p];
            float w0 = __int_as_float(e0.y);
            if (INF == 0) {
                float2 r0 = *(reinterpret_cast<const float2*>(inf + (size_t)e0.x * D) + lane);
                ax += w0 * r0.x; ay += w0 * r0.y;
            } else {
                unsigned int q0 = *reinterpret_cast<const unsigned int*>(inh + (size_t)e0.x * D + lane * 2);
                float2 f0 = h2f2(q0);
                ax += w0 * f0.x; ay += w0 * f0.y;
            }
        }
        if (OUTM == 0) {
            float* out = (float*)outv;
            if (BIAS) {
                float2 b = *(reinterpret_cast<const float2*>(bias) + lane);
                ax += b.x; ay += b.y;
            }
            f32x2v res = {ax, ay};
            __builtin_nontemporal_store(res,
                reinterpret_cast<f32x2v*>(out + (size_t)node * D) + lane);
        } else {
            u16* out = (u16*)outv;  // fp16 [N, 128]
            u16x2v hv = {f2h(ax), f2h(ay)};
            __builtin_nontemporal_store(hv,
                reinterpret_cast<u16x2v*>(out + (size_t)node * D + lane * 2));
        }
    }
}

// ---------------------------------------------------------------------------
// fp16 MFMA GEMM with fp16-hilo weights.
// R9: staging loop reverted to the verified R7 form (R8 pipelining regressed).
// NEW: coalesced epilogue — C-tile staged through LDS (reusing the staging
// buffer), then stored as full 256B rows (uint4/lane). Kills the partial-line
// RMW traffic (WRITE was 95 MB for a 25.6 MB output).
// ---------------------------------------------------------------------------

template <int OUT, bool BIAS, bool RELU>
__global__ __launch_bounds__(256) void k_gemm_h(const u16* __restrict__ Ap,
                                                const u16* __restrict__ Bp,
                                                const float* __restrict__ bias,
                                                void* __restrict__ Cv,
                                                int M, int K, int NN) {
    const int KP2 = 2 * K;
    // single LDS pool: As = S[0..4351], Bs = S[4352..13055]; epilogue reuses
    // S as Cs[64][136] (8704 u16).
    __shared__ u16 S[13056];
    u16* As = S;
    u16* Bs = S + 4352;
    int tid = threadIdx.x;
    int bm = blockIdx.y * 128;
    int bn = blockIdx.x * 128;
    int l = tid & 63;
    int w = tid >> 6;
    int wr = w >> 1, wc = w & 1;

    f32x4 zero = {0.f, 0.f, 0.f, 0.f};
    f32x4 acc[4][4];
    #pragma unroll
    for (int i = 0; i < 4; i++)
        #pragma unroll
        for (int j = 0; j < 4; j++) acc[i][j] = zero;

    for (int k0 = 0; k0 < K; k0 += 32) {
        #pragma unroll
        for (int q = 0; q < 2; q++) {
            int idx = tid + q * 256;
            int r = idx >> 2, o = idx & 3;
            int gr = bm + r;
            uint4 va = make_uint4(0u, 0u, 0u, 0u);
            if (gr < M)
                va = *reinterpret_cast<const uint4*>(Ap + (size_t)gr * K + k0 + o * 8);
            *reinterpret_cast<uint4*>(&As[(r >> 4) * 544 + o * 136 + (r & 15) * 8]) = va;
        }
        #pragma unroll
        for (int q = 0; q < 4; q++) {
            int idx = tid + q * 256;
            int r = idx >> 3, oct = idx & 7;
            int hf = oct >> 2, o = oct & 3;
            uint4 vb = *reinterpret_cast<const uint4*>(
                Bp + (size_t)(bn + r) * KP2 + hf * K + k0 + o * 8);
            *reinterpret_cast<uint4*>(
                &Bs[hf * 4352 + (r >> 4) * 544 + o * 136 + (r & 15) * 8]) = vb;
        }
        __syncthreads();
        int fro = (l >> 4) * 136 + (l & 15) * 8;
        f16x8 a[4], bh[4], bl[4];
        #pragma unroll
        for (int i = 0; i < 4; i++)
            a[i] = *reinterpret_cast<const f16x8*>(&As[(wr * 4 + i) * 544 + fro]);
        #pragma unroll
        for (int j = 0; j < 4; j++) {
            bh[j] = *reinterpret_cast<const f16x8*>(&Bs[(wc * 4 + j) * 544 + fro]);
            bl[j] = *reinterpret_cast<const f16x8*>(&Bs[4352 + (wc * 4 + j) * 544 + fro]);
        }
        #pragma unroll
        for (int i = 0; i < 4; i++)
            #pragma unroll
            for (int j = 0; j < 4; j++) {
                acc[i][j] = __builtin_amdgcn_mfma_f32_16x16x32_f16(a[i], bh[j], acc[i][j], 0, 0, 0);
                acc[i][j] = __builtin_amdgcn_mfma_f32_16x16x32_f16(a[i], bl[j], acc[i][j], 0, 0, 0);
            }
        __syncthreads();
    }

    int cl = l & 15;
    int rq = (l >> 4) * 4;
    float bv[4];
    #pragma unroll
    for (int j = 0; j < 4; j++) {
        int gc = bn + wc * 64 + j * 16 + cl;
        bv[j] = BIAS ? bias[gc] : 0.f;
    }

    if (OUT == 1) {
        // Coalesced epilogue: two 64-row halves through LDS.
        u16* Cs = S;             // [64][136] u16
        u16* outp = (u16*)Cv;
        #pragma unroll
        for (int half = 0; half < 2; ++half) {
            if (wr == half) {
                #pragma unroll
                for (int i = 0; i < 4; i++)
                    #pragma unroll
                    for (int r = 0; r < 4; r++) {
                        int lrow = i * 16 + rq + r;          // 0..63
                        #pragma unroll
                        for (int j = 0; j < 4; j++) {
                            float v = acc[i][j][r];
                            if (BIAS) v += bv[j];
                            if (RELU) v = fmaxf(v, 0.f);
                            Cs[lrow * 136 + wc * 64 + j * 16 + cl] = f2h(v);
                        }
                    }
            }
            __syncthreads();
            int srow = tid >> 4;                 // 0..15
            int scol = (tid & 15) * 8;           // 0..120 (u16 units)
            #pragma unroll
            for (int p = 0; p < 4; ++p) {
                int lrow = p * 16 + srow;        // 0..63
                int grow = bm + half * 64 + lrow;
                if (grow < M) {
                    *reinterpret_cast<uint4*>(outp + (size_t)grow * NN + bn + scol) =
                        *reinterpret_cast<const uint4*>(&Cs[lrow * 136 + scol]);
                }
            }
            __syncthreads();
        }
    } else {
        // f32 path (unused by current launcher) — original scalar stores.
        #pragma unroll
        for (int i = 0; i < 4; i++) {
            #pragma unroll
            for (int r = 0; r < 4; r++) {
                int grow = bm + wr * 64 + i * 16 + rq + r;
                if (grow >= M) continue;
                #pragma unroll
                for (int j = 0; j < 4; j++) {
                    int gc = bn + wc * 64 + j * 16 + cl;
                    float v = acc[i][j][r];
                    if (BIAS) v += bv[j];
                    if (RELU) v = fmaxf(v, 0.f);
                    ((float*)Cv)[(size_t)grow * NN + gc] = v;
                }
            }
        }
    }
}

// ---------------------------------------------------------------------------
// launch
// ---------------------------------------------------------------------------

extern "C" void kernel_launch(void* const* d_in, const int* in_sizes, int n_in,
                              void* d_out, int out_size, void* d_ws, size_t ws_size,
                              hipStream_t stream) {
    const float* x   = (const float*)d_in[0];
    const int*   ei  = (const int*)d_in[1];
    const float* wts = (const float*)d_in[2];
    const float* W1  = (const float*)d_in[3];
    const float* b1  = (const float*)d_in[4];
    const float* W2  = (const float*)d_in[5];
    const float* b2  = (const float*)d_in[6];
    const float* W3  = (const float*)d_in[7];
    const float* b3  = (const float*)d_in[8];
    float* out = (float*)d_out;
    const int* src = ei;
    const int* dst = ei + N_EDGES;

    // Layout identical to the verified R1/R5/R7 kernels.
    float* bufA   = (float*)d_ws;                         // fp16 [N,256] max
    float* bufB   = bufA + (size_t)N_NODES * D_HID;       // fp16 [N,256] max (51.2 MB)
    float* ew     = bufB + (size_t)N_NODES * D_HID;       // [E]
    float* dinv   = ew + N_EDGES;                         // [N]
    int*   cnt    = (int*)(dinv + N_NODES);               // [N] (unused now)
    int*   rank   = cnt + N_NODES;                        // [E]
    int*   rowptr = rank + N_EDGES;                       // [N+1]
    int2*  ecsr   = (int2*)(rowptr + (N_NODES + 2));      // [E] packed {src, w}
    u16*   Wb1    = (u16*)(ecsr + N_EDGES);               // [256*256]
    u16*   Wb2    = Wb1 + 256 * 256;                      // [256*512]
    u16*   Wb3    = Wb2 + 256 * 512;                      // [128*512]
    int*   bsum   = (int*)(Wb3 + 128 * 512);              // [NB_SCAN]
    // degcnt (u64[N], 400 KB) in bufB's LOWER half; xh (fp16 [N,128], 12.8 MB)
    // in bufB's UPPER half (offset 25.6 MB). Both dead before gemm1 writes
    // bufB's first 25.6 MB.
    u64*   degcnt = (u64*)bufB;
    u16*   xh     = (u16*)(bufB + (size_t)N_NODES * D_HID / 2);

    (void)hipMemsetAsync(degcnt, 0, sizeof(u64) * N_NODES, stream);

    int ethreads = 256;
    int eblocks = (N_EDGES + ethreads - 1) / ethreads;
    k_setup0<<<eblocks, ethreads, 0, stream>>>(dst, wts, ew, rank, degcnt,
                                               x, xh, W1, W2, W3, Wb1, Wb2, Wb3);
    k_scan1<<<NB_SCAN, 256, 0, stream>>>(degcnt, rowptr, bsum);
    k_scan23<<<NB_SCAN, 256, 0, stream>>>(bsum, rowptr, degcnt, dinv);
    k_fill2<<<eblocks, ethreads, 0, stream>>>(src, dst, ew, rank, rowptr, dinv, ecsr);

    int aggBlocks = (N_NODES + 3) / 4;
    int gy = (N_NODES + 127) / 128;  // 391

    // agg1: xh (fp16) -> bufA fp16 [N,128]
    k_agg<128, 1, 1, false><<<aggBlocks, 256, 0, stream>>>(xh, rowptr, ecsr, dinv, nullptr, bufA);
    // gemm1: h1 = relu(bufA @ W1 + b1) -> bufB fp16 [N,256]
    {
        dim3 g(2, gy);
        k_gemm_h<1, true, true><<<g, 256, 0, stream>>>((const u16*)bufA, Wb1, b1, bufB,
                                                       N_NODES, D_IN, D_HID);
    }
    // agg2: bufB fp16 -> bufA fp16 [N,256]
    k_agg<256, 1, 1, false><<<aggBlocks, 256, 0, stream>>>(bufB, rowptr, ecsr, dinv, nullptr, bufA);
    // gemm2: h2 = relu(bufA @ W2 + b2) -> bufB fp16 [N,256]
    {
        dim3 g(2, gy);
        k_gemm_h<1, true, true><<<g, 256, 0, stream>>>((const u16*)bufA, Wb2, b2, bufB,
                                                       N_NODES, D_HID, D_HID);
    }
    // gemm3: y3 = bufB @ W3 -> bufA fp16 [N,128]
    {
        dim3 g(1, gy);
        k_gemm_h<1, false, false><<<g, 256, 0, stream>>>((const u16*)bufB, Wb3, nullptr, bufA,
                                                         N_NODES, D_HID, D_OUT);
    }
    // agg3: bufA fp16 -> out f32 + b3
    k_agg<128, 1, 0, true><<<aggBlocks, 256, 0, stream>>>(bufA, rowptr, ecsr, dinv, b3, out);
}